// Round 10
// baseline (450.381 us; speedup 1.0000x reference)
//
#include <hip/hip_runtime.h>
#include <hip/hip_bf16.h>
#include <math.h>

#define T_STEPS 100
#define B 256
#define Q 2048
#define H 1024
#define NIN 4096

typedef __attribute__((ext_vector_type(8))) short bf16x8;
typedef __attribute__((ext_vector_type(4))) float f32x4;
typedef unsigned long long u64;

/* LDS layout (bytes) */
#define HLDS0_OFF 0                     /* 16 students x 512 bf16, swizzled: 16 KB */
#define HLDS1_OFF 16384                 /* second K half: 16 KB                    */
#define LOGIT_OFF 32768                 /* 4 waves x 16 f32: 256 B                 */
#define GO_OFF    (32768 + 256)         /* monotonic go word: 4 B                  */
#define SMEM_BYTES (GO_OFF + 16)

/* workspace layout (bytes) */
#define H0_OFF 0
#define H1_OFF (512 * 1024)
#define LP_OFF (1024 * 1024)            /* lp[100][16 rg][256 s] f32 = 1.6 MB */
#define FLAG_OFF (LP_OFF + 1638400)     /* 16 sgs x 16 flags (64 B/sg line)   */

#define AGENT __HIP_MEMORY_SCOPE_AGENT

__device__ inline unsigned short f2bf(float f) {
    union { float f; unsigned int u; } c; c.f = f;
    unsigned int u = c.u + 0x7fffu + ((c.u >> 16) & 1u);
    return (unsigned short)(u >> 16);
}

__global__ void ws_init(unsigned* __restrict__ flags) {
    int idx = blockIdx.x * blockDim.x + threadIdx.x;
    if (idx < 16 * 16) flags[idx] = 0u;
}

__global__ __launch_bounds__(256, 1) void rnn_persistent(
    const int* __restrict__ x_idx, const int* __restrict__ y_idx,
    const float* __restrict__ truth,
    const float* __restrict__ Wm, const float* __restrict__ bm,
    const float* __restrict__ Wx, const float* __restrict__ bx_,
    const float* __restrict__ Wy, const float* __restrict__ by,
    const float* __restrict__ b_start,
    __hip_bfloat16* __restrict__ h0buf, __hip_bfloat16* __restrict__ h1buf,
    float* __restrict__ lp, unsigned* __restrict__ flags,
    float* __restrict__ out)
{
    extern __shared__ char lds[];

    const int tid = threadIdx.x;
    const int bid = blockIdx.x;
    const int rg = bid & 15;          /* row group: rows [rg*64, +64)  */
    const int sg = bid >> 4;          /* student group: [sg*16, +16)   */
    const int sbase = sg * 16;
    const int w  = tid >> 6;          /* wave 0..3 -> rows w*16..+15   */
    const int l  = tid & 63;
    const int lr = l & 15;
    const int g  = l >> 4;

    unsigned* sgf = flags + sg * 16;                 /* 64 B line per sg */
    volatile unsigned* go_lds = (volatile unsigned*)&lds[GO_OFF];

    if (tid == 0) *go_lds = 0u;   /* init before first arrive-sync */

    /* ---- one-time setup ---- */
    /* A-fragments for my wave's 16 output rows -> registers (32 x bf16x8). */
    bf16x8 a_frag[32];
    {
        const int row = rg * 64 + w * 16 + lr;
        const float* wrow = &Wm[(size_t)row * H];
        #pragma unroll
        for (int half = 0; half < 2; ++half) {
            #pragma unroll
            for (int kk = 0; kk < 16; ++kk) {
                int k0 = (half * 64 + kk * 4 + g) * 8;
                float4 v0 = *reinterpret_cast<const float4*>(&wrow[k0]);
                float4 v1 = *reinterpret_cast<const float4*>(&wrow[k0 + 4]);
                bf16x8 f;
                f[0] = (short)f2bf(v0.x); f[1] = (short)f2bf(v0.y);
                f[2] = (short)f2bf(v0.z); f[3] = (short)f2bf(v0.w);
                f[4] = (short)f2bf(v1.x); f[5] = (short)f2bf(v1.y);
                f[6] = (short)f2bf(v1.z); f[7] = (short)f2bf(v1.w);
                a_frag[half * 16 + kk] = f;
            }
        }
    }
    /* h0 = b_start broadcast (zeros @ W_start.T == 0), agent-scope stores */
    {
        int s = tid >> 4, c8 = tid & 15;
        union { unsigned short s4[4]; u64 u; } pk;
        #pragma unroll
        for (int e = 0; e < 4; ++e) pk.s4[e] = f2bf(b_start[rg * 64 + c8 * 4 + e]);
        __hip_atomic_store((u64*)&h0buf[(size_t)(sbase + s) * H + rg * 64 + c8 * 4],
                           pk.u, __ATOMIC_RELAXED, AGENT);
    }
    /* per-lane row-invariant bias */
    float bias_r[4];
    #pragma unroll
    for (int r = 0; r < 4; ++r) {
        int gi = rg * 64 + w * 16 + g * 4 + r;
        bias_r[r] = bm[gi] + bx_[gi];
    }
    /* gathers for t = 0 */
    float wx_r[4], wy_r[4];
    {
        int xc = x_idx[sbase + lr];
        int yc = y_idx[sbase + lr];
        #pragma unroll
        for (int r = 0; r < 4; ++r) {
            int gi = rg * 64 + w * 16 + g * 4 + r;
            wx_r[r] = Wx[(size_t)gi * NIN + xc];
            wy_r[r] = Wy[(size_t)yc * H + gi];
        }
    }

    /* ---- initial barrier: arrive (drain+sync+flag), wave0 polls, LDS relay ---- */
    {
        asm volatile("s_waitcnt vmcnt(0)" ::: "memory");
        __syncthreads();
        if (tid == 0) __hip_atomic_store(&sgf[rg], 1u, __ATOMIC_RELAXED, AGENT);
        if (w == 0) {
            unsigned v;
            do { v = (l < 16) ? __hip_atomic_load(&sgf[l], __ATOMIC_RELAXED, AGENT) : 1u; }
            while (!__all(v >= 1u));
            if (tid == 0) *go_lds = 1u;
        } else {
            while (*go_lds < 1u) {}
        }
    }

    /* ---- recurrence ---- */
    for (int t = 0; t < T_STEPS; ++t) {
        const __hip_bfloat16* hc = (t & 1) ? h1buf : h0buf;
        __hip_bfloat16*       hn = (t & 1) ? h0buf : h1buf;

        /* prefetch both h halves into registers (agent atomic loads, MALL) */
        u64 r0[8], r1[8];
        #pragma unroll
        for (int it = 0; it < 4; ++it) {
            int q = it * 256 + tid;
            int srow = q >> 6, sl = q & 63;
            const u64* src = (const u64*)&hc[(size_t)(sbase + srow) * H + sl * 8];
            r0[2 * it]     = __hip_atomic_load(src,     __ATOMIC_RELAXED, AGENT);
            r0[2 * it + 1] = __hip_atomic_load(src + 1, __ATOMIC_RELAXED, AGENT);
        }
        #pragma unroll
        for (int it = 0; it < 4; ++it) {
            int q = it * 256 + tid;
            int srow = q >> 6, sl = q & 63;
            const u64* src = (const u64*)&hc[(size_t)(sbase + srow) * H + 512 + sl * 8];
            r1[2 * it]     = __hip_atomic_load(src,     __ATOMIC_RELAXED, AGENT);
            r1[2 * it + 1] = __hip_atomic_load(src + 1, __ATOMIC_RELAXED, AGENT);
        }

        /* stage BOTH halves (separate LDS buffers), single sync */
        #pragma unroll
        for (int it = 0; it < 4; ++it) {
            int q = it * 256 + tid;
            int srow = q >> 6, sl = q & 63;
            union { u64 u[2]; bf16x8 v; } cvt;
            cvt.u[0] = r0[2 * it]; cvt.u[1] = r0[2 * it + 1];
            *reinterpret_cast<bf16x8*>(
                &lds[HLDS0_OFF + srow * 1024 + ((sl ^ (srow & 7)) << 4)]) = cvt.v;
        }
        #pragma unroll
        for (int it = 0; it < 4; ++it) {
            int q = it * 256 + tid;
            int srow = q >> 6, sl = q & 63;
            union { u64 u[2]; bf16x8 v; } cvt;
            cvt.u[0] = r1[2 * it]; cvt.u[1] = r1[2 * it + 1];
            *reinterpret_cast<bf16x8*>(
                &lds[HLDS1_OFF + srow * 1024 + ((sl ^ (srow & 7)) << 4)]) = cvt.v;
        }
        __syncthreads();

        /* 32 MFMAs, two independent acc chains (even/odd) for ILP */
        f32x4 acc0 = {0.f, 0.f, 0.f, 0.f};
        f32x4 acc1 = {0.f, 0.f, 0.f, 0.f};
        #pragma unroll
        for (int kk = 0; kk < 16; kk += 2) {
            bf16x8 b0 = *reinterpret_cast<const bf16x8*>(
                &lds[HLDS0_OFF + lr * 1024 + ((((kk    ) * 4 + g) ^ (lr & 7)) << 4)]);
            acc0 = __builtin_amdgcn_mfma_f32_16x16x32_bf16(a_frag[kk],     b0, acc0, 0, 0, 0);
            bf16x8 b1 = *reinterpret_cast<const bf16x8*>(
                &lds[HLDS0_OFF + lr * 1024 + ((((kk + 1) * 4 + g) ^ (lr & 7)) << 4)]);
            acc1 = __builtin_amdgcn_mfma_f32_16x16x32_bf16(a_frag[kk + 1], b1, acc1, 0, 0, 0);
        }
        #pragma unroll
        for (int kk = 0; kk < 16; kk += 2) {
            bf16x8 b0 = *reinterpret_cast<const bf16x8*>(
                &lds[HLDS1_OFF + lr * 1024 + ((((kk    ) * 4 + g) ^ (lr & 7)) << 4)]);
            acc0 = __builtin_amdgcn_mfma_f32_16x16x32_bf16(a_frag[16 + kk],     b0, acc0, 0, 0, 0);
            bf16x8 b1 = *reinterpret_cast<const bf16x8*>(
                &lds[HLDS1_OFF + lr * 1024 + ((((kk + 1) * 4 + g) ^ (lr & 7)) << 4)]);
            acc1 = __builtin_amdgcn_mfma_f32_16x16x32_bf16(a_frag[16 + kk + 1], b1, acc1, 0, 0, 0);
        }

        /* epilogue */
        float hv[4];
        #pragma unroll
        for (int r = 0; r < 4; ++r)
            hv[r] = tanhf(acc0[r] + acc1[r] + bias_r[r] + wx_r[r]);

        {   /* DIRECT h_next store: lane's 4 rows are contiguous for student lr.
               h[sbase+lr][rg*64 + w*16 + g*4 .. +4] = 8 B, 8B-aligned. */
            union { unsigned short s4[4]; u64 u; } pk;
            #pragma unroll
            for (int r = 0; r < 4; ++r) pk.s4[r] = f2bf(hv[r]);
            __hip_atomic_store(
                (u64*)&hn[(size_t)(sbase + lr) * H + rg * 64 + w * 16 + g * 4],
                pk.u, __ATOMIC_RELAXED, AGENT);
        }
        {   /* logit partial: wave's 16 rows for student lr */
            float p = hv[0] * wy_r[0] + hv[1] * wy_r[1] + hv[2] * wy_r[2] + hv[3] * wy_r[3];
            p += __shfl_down(p, 32);
            p += __shfl_down(p, 16);
            if (l < 16)
                *reinterpret_cast<float*>(&lds[LOGIT_OFF + (w * 16 + l) * 4]) = p;
        }
        __syncthreads();
        if (tid < 16) {   /* this block's logit partial: plain store, no RMW */
            const float* lg = reinterpret_cast<const float*>(&lds[LOGIT_OFF]);
            float ps = lg[tid] + lg[16 + tid] + lg[32 + tid] + lg[48 + tid];
            __hip_atomic_store(&lp[(size_t)(t * 16 + rg) * B + sbase + tid],
                               ps, __ATOMIC_RELAXED, AGENT);
        }

        /* ---- barrier: arrive -> gathers -> single-hop detect + LDS relay ---- */
        {
            const unsigned fval = (unsigned)(t + 2);
            asm volatile("s_waitcnt vmcnt(0)" ::: "memory");  /* h + lp stores at MALL */
            __syncthreads();
            if (tid == 0) __hip_atomic_store(&sgf[rg], fval, __ATOMIC_RELAXED, AGENT);

            /* next-step gather chain (all waves) — hidden under the poll */
            {
                int tn = (t + 1 < T_STEPS) ? t + 1 : t;
                int xc = x_idx[tn * B + sbase + lr];
                int yc = y_idx[tn * B + sbase + lr];
                #pragma unroll
                for (int r = 0; r < 4; ++r) {
                    int gi = rg * 64 + w * 16 + g * 4 + r;
                    wx_r[r] = Wx[(size_t)gi * NIN + xc];
                    wy_r[r] = Wy[(size_t)yc * H + gi];
                }
            }

            if (w == 0) {
                unsigned v;
                do { v = (l < 16) ? __hip_atomic_load(&sgf[l], __ATOMIC_RELAXED, AGENT) : fval; }
                while (!__all(v >= fval));
                if (tid == 0) *go_lds = fval;
            } else {
                while (*go_lds < fval) {}
            }
            /* no trailing __syncthreads: each wave proceeds to its own h loads;
               stage-sync realigns before MFMA. WAR-safe (go publishes only after
               all waves passed arrive-sync). */
        }
    }

    /* ---- final: block (rg,sg) handles t = rg, rg+16, ... for its 16 students ---- */
    {
        int ti = tid >> 4, s = tid & 15;
        int t = rg + ti * 16;
        if (t < T_STEPS) {
            int idx = t * B + sbase + s;
            float lgv = 0.f;
            #pragma unroll
            for (int rgi = 0; rgi < 16; ++rgi)
                lgv += __hip_atomic_load(&lp[(size_t)(t * 16 + rgi) * B + sbase + s],
                                         __ATOMIC_RELAXED, AGENT);
            int yc = y_idx[idx];
            lgv += by[yc];
            float pred = 1.f / (1.f + expf(-lgv));
            float tv = truth[idx];
            float e = log1pf(expf(-fabsf(lgv)));
            float ls_pos = fminf(lgv, 0.f) - e;
            float ls_neg = fminf(-lgv, 0.f) - e;
            out[idx] = pred;
            out[T_STEPS * B + idx] = -(tv * ls_pos + (1.f - tv) * ls_neg);
        }
    }
}

extern "C" void kernel_launch(void* const* d_in, const int* in_sizes, int n_in,
                              void* d_out, int out_size, void* d_ws, size_t ws_size,
                              hipStream_t stream) {
    const int*   x_idx   = (const int*)d_in[0];
    const int*   y_idx   = (const int*)d_in[1];
    const float* truth   = (const float*)d_in[2];
    const float* Wm      = (const float*)d_in[3];
    const float* bm      = (const float*)d_in[4];
    const float* Wx      = (const float*)d_in[5];
    const float* bx_     = (const float*)d_in[6];
    const float* Wy      = (const float*)d_in[7];
    const float* by      = (const float*)d_in[8];
    /* d_in[9] = W_start: dead (multiplied by zeros) */
    const float* b_start = (const float*)d_in[10];
    float* out = (float*)d_out;

    __hip_bfloat16* h0buf = (__hip_bfloat16*)((char*)d_ws + H0_OFF);
    __hip_bfloat16* h1buf = (__hip_bfloat16*)((char*)d_ws + H1_OFF);
    float*          lp    = (float*)((char*)d_ws + LP_OFF);
    unsigned*       flags = (unsigned*)((char*)d_ws + FLAG_OFF);

    ws_init<<<1, 256, 0, stream>>>(flags);

    /* plain launch: 256 blocks on 256 CUs are unconditionally co-resident. */
    rnn_persistent<<<dim3(256), dim3(256), SMEM_BYTES, stream>>>(
        x_idx, y_idx, truth, Wm, bm, Wx, bx_, Wy, by, b_start,
        h0buf, h1buf, lp, flags, out);
}

// Round 11
// 414.118 us; speedup vs baseline: 1.0876x; 1.0876x over previous
//
#include <hip/hip_runtime.h>
#include <hip/hip_bf16.h>
#include <math.h>

#define T_STEPS 100
#define B 256
#define Q 2048
#define H 1024
#define NIN 4096

typedef __attribute__((ext_vector_type(8))) short bf16x8;
typedef __attribute__((ext_vector_type(4))) short bf16x4;
typedef __attribute__((ext_vector_type(4))) float f32x4;
typedef unsigned long long u64;

/* LDS layout (bytes): both h halves resident -> 2 syncs/step */
#define HLDS0_OFF 0                     /* 16 students x 512 bf16, swizzled: 16 KB */
#define HLDS1_OFF 16384                 /* second K half: 16 KB                    */
#define HOUT_OFF  32768                 /* 16 students x 64 cols bf16: 2 KB        */
#define LOGIT_OFF (32768 + 2048)        /* 4 waves x 16 f32: 256 B                 */
#define SMEM_BYTES (LOGIT_OFF + 256)    /* 35328 */

/* workspace layout (bytes) */
#define H0_OFF 0
#define H1_OFF (512 * 1024)
#define LP_OFF (1024 * 1024)            /* lp[100][16 rg][256 s] f32 = 1.6 MB  */
#define FLAG_OFF (LP_OFF + 1638400)     /* 16 sgs x 64 u32 (256 B/sg)          */

#define AGENT __HIP_MEMORY_SCOPE_AGENT

__device__ inline unsigned short f2bf(float f) {
    union { float f; unsigned int u; } c; c.f = f;
    unsigned int u = c.u + 0x7fffu + ((c.u >> 16) & 1u);
    return (unsigned short)(u >> 16);
}

__global__ void ws_init(unsigned* __restrict__ flags) {
    int idx = blockIdx.x * blockDim.x + threadIdx.x;
    if (idx < 16 * 64) flags[idx] = 0u;
}

__global__ __launch_bounds__(256, 1) void rnn_persistent(
    const int* __restrict__ x_idx, const int* __restrict__ y_idx,
    const float* __restrict__ truth,
    const float* __restrict__ Wm, const float* __restrict__ bm,
    const float* __restrict__ Wx, const float* __restrict__ bx_,
    const float* __restrict__ Wy, const float* __restrict__ by,
    const float* __restrict__ b_start,
    __hip_bfloat16* __restrict__ h0buf, __hip_bfloat16* __restrict__ h1buf,
    float* __restrict__ lp, unsigned* __restrict__ flags,
    float* __restrict__ out)
{
    extern __shared__ char lds[];

    const int tid = threadIdx.x;
    const int bid = blockIdx.x;
    const int rg = bid & 15;          /* row group: rows [rg*64, +64)  */
    const int sg = bid >> 4;          /* student group: [sg*16, +16)   */
    const int sbase = sg * 16;
    const int w  = tid >> 6;          /* wave 0..3 -> rows w*16..+15   */
    const int l  = tid & 63;
    const int lr = l & 15;
    const int g  = l >> 4;

    unsigned* sgf = flags + sg * 64;  /* [0..15] arrive flags, [32] go word */

    /* ---- one-time setup ---- */
    /* A-fragments for my wave's 16 output rows -> registers (32 x bf16x8). */
    bf16x8 a_frag[32];
    {
        const int row = rg * 64 + w * 16 + lr;
        const float* wrow = &Wm[(size_t)row * H];
        #pragma unroll
        for (int half = 0; half < 2; ++half) {
            #pragma unroll
            for (int kk = 0; kk < 16; ++kk) {
                int k0 = (half * 64 + kk * 4 + g) * 8;
                float4 v0 = *reinterpret_cast<const float4*>(&wrow[k0]);
                float4 v1 = *reinterpret_cast<const float4*>(&wrow[k0 + 4]);
                bf16x8 f;
                f[0] = (short)f2bf(v0.x); f[1] = (short)f2bf(v0.y);
                f[2] = (short)f2bf(v0.z); f[3] = (short)f2bf(v0.w);
                f[4] = (short)f2bf(v1.x); f[5] = (short)f2bf(v1.y);
                f[6] = (short)f2bf(v1.z); f[7] = (short)f2bf(v1.w);
                a_frag[half * 16 + kk] = f;
            }
        }
    }
    /* h0 = b_start broadcast (zeros @ W_start.T == 0), agent-scope stores */
    {
        int s = tid >> 4, c8 = tid & 15;
        union { unsigned short s4[4]; u64 u; } pk;
        #pragma unroll
        for (int e = 0; e < 4; ++e) pk.s4[e] = f2bf(b_start[rg * 64 + c8 * 4 + e]);
        __hip_atomic_store((u64*)&h0buf[(size_t)(sbase + s) * H + rg * 64 + c8 * 4],
                           pk.u, __ATOMIC_RELAXED, AGENT);
    }
    /* per-lane row-invariant bias */
    float bias_r[4];
    #pragma unroll
    for (int r = 0; r < 4; ++r) {
        int gi = rg * 64 + w * 16 + g * 4 + r;
        bias_r[r] = bm[gi] + bx_[gi];
    }
    /* gathers for t = 0 */
    float wx_r[4], wy_r[4];
    {
        int xc = x_idx[sbase + lr];
        int yc = y_idx[sbase + lr];
        #pragma unroll
        for (int r = 0; r < 4; ++r) {
            int gi = rg * 64 + w * 16 + g * 4 + r;
            wx_r[r] = Wx[(size_t)gi * NIN + xc];
            wy_r[r] = Wy[(size_t)yc * H + gi];
        }
    }

    /* ---- initial barrier (hybrid: parallel flag stores + rg0 aggregator) ---- */
    {
        asm volatile("s_waitcnt vmcnt(0)" ::: "memory");
        __syncthreads();
        if (tid == 0) __hip_atomic_store(&sgf[rg], 1u, __ATOMIC_RELAXED, AGENT);
        if (rg == 0) {
            if (tid < 64) {
                unsigned v;
                do {
                    v = (tid < 16) ? __hip_atomic_load(&sgf[tid], __ATOMIC_RELAXED, AGENT) : 1u;
                } while (!__all(v >= 1u));
                if (tid == 0) __hip_atomic_store(&sgf[32], 1u, __ATOMIC_RELAXED, AGENT);
            }
        } else if (tid == 0) {
            while (__hip_atomic_load(&sgf[32], __ATOMIC_RELAXED, AGENT) < 1u) {}
        }
        __syncthreads();
    }

    /* ---- recurrence ---- */
    for (int t = 0; t < T_STEPS; ++t) {
        const __hip_bfloat16* hc = (t & 1) ? h1buf : h0buf;
        __hip_bfloat16*       hn = (t & 1) ? h0buf : h1buf;

        /* prefetch both h halves: 16B device-coherent loads (sc0 sc1 = L1+L2
           bypass, same bits as agent-scope atomics) — HALF the MALL request
           count of the former 8B atomic pairs. Issue all 8, wait once. */
        bf16x8 hv0[4], hv1[4];
        #pragma unroll
        for (int it = 0; it < 4; ++it) {
            int q = it * 256 + tid;
            int srow = q >> 6, sl = q & 63;
            const __hip_bfloat16* p = &hc[(size_t)(sbase + srow) * H + sl * 8];
            asm volatile("global_load_dwordx4 %0, %1, off sc0 sc1"
                         : "=v"(hv0[it]) : "v"(p));
        }
        #pragma unroll
        for (int it = 0; it < 4; ++it) {
            int q = it * 256 + tid;
            int srow = q >> 6, sl = q & 63;
            const __hip_bfloat16* p = &hc[(size_t)(sbase + srow) * H + 512 + sl * 8];
            asm volatile("global_load_dwordx4 %0, %1, off sc0 sc1"
                         : "=v"(hv1[it]) : "v"(p));
        }
        asm volatile("s_waitcnt vmcnt(0)" ::: "memory");
        __builtin_amdgcn_sched_barrier(0);

        /* stage BOTH halves (separate LDS buffers), single sync */
        #pragma unroll
        for (int it = 0; it < 4; ++it) {
            int q = it * 256 + tid;
            int srow = q >> 6, sl = q & 63;
            *reinterpret_cast<bf16x8*>(
                &lds[HLDS0_OFF + srow * 1024 + ((sl ^ (srow & 7)) << 4)]) = hv0[it];
        }
        #pragma unroll
        for (int it = 0; it < 4; ++it) {
            int q = it * 256 + tid;
            int srow = q >> 6, sl = q & 63;
            *reinterpret_cast<bf16x8*>(
                &lds[HLDS1_OFF + srow * 1024 + ((sl ^ (srow & 7)) << 4)]) = hv1[it];
        }
        __syncthreads();

        /* 32 MFMAs, two independent acc chains (even/odd) for ILP */
        f32x4 acc0 = {0.f, 0.f, 0.f, 0.f};
        f32x4 acc1 = {0.f, 0.f, 0.f, 0.f};
        #pragma unroll
        for (int kk = 0; kk < 16; kk += 2) {
            bf16x8 b0 = *reinterpret_cast<const bf16x8*>(
                &lds[HLDS0_OFF + lr * 1024 + ((((kk    ) * 4 + g) ^ (lr & 7)) << 4)]);
            acc0 = __builtin_amdgcn_mfma_f32_16x16x32_bf16(a_frag[kk],     b0, acc0, 0, 0, 0);
            bf16x8 b1 = *reinterpret_cast<const bf16x8*>(
                &lds[HLDS0_OFF + lr * 1024 + ((((kk + 1) * 4 + g) ^ (lr & 7)) << 4)]);
            acc1 = __builtin_amdgcn_mfma_f32_16x16x32_bf16(a_frag[kk + 1], b1, acc1, 0, 0, 0);
        }
        #pragma unroll
        for (int kk = 0; kk < 16; kk += 2) {
            bf16x8 b0 = *reinterpret_cast<const bf16x8*>(
                &lds[HLDS1_OFF + lr * 1024 + ((((kk    ) * 4 + g) ^ (lr & 7)) << 4)]);
            acc0 = __builtin_amdgcn_mfma_f32_16x16x32_bf16(a_frag[16 + kk],     b0, acc0, 0, 0, 0);
            bf16x8 b1 = *reinterpret_cast<const bf16x8*>(
                &lds[HLDS1_OFF + lr * 1024 + ((((kk + 1) * 4 + g) ^ (lr & 7)) << 4)]);
            acc1 = __builtin_amdgcn_mfma_f32_16x16x32_bf16(a_frag[16 + kk + 1], b1, acc1, 0, 0, 0);
        }

        /* epilogue */
        float hv[4];
        #pragma unroll
        for (int r = 0; r < 4; ++r)
            hv[r] = tanhf(acc0[r] + acc1[r] + bias_r[r] + wx_r[r]);

        {   /* h_out tile -> LDS (swizzled by student) */
            int row0  = w * 16 + g * 4;
            int chunk = row0 >> 3;
            bf16x4 b4;
            b4[0] = (short)f2bf(hv[0]); b4[1] = (short)f2bf(hv[1]);
            b4[2] = (short)f2bf(hv[2]); b4[3] = (short)f2bf(hv[3]);
            int byte = HOUT_OFF + lr * 128 + ((chunk ^ (lr & 7)) << 4) + ((row0 & 7) << 1);
            *reinterpret_cast<bf16x4*>(&lds[byte]) = b4;
        }
        {   /* logit partial: wave's 16 rows for student lr */
            float p = hv[0] * wy_r[0] + hv[1] * wy_r[1] + hv[2] * wy_r[2] + hv[3] * wy_r[3];
            p += __shfl_down(p, 32);
            p += __shfl_down(p, 16);
            if (l < 16)
                *reinterpret_cast<float*>(&lds[LOGIT_OFF + (w * 16 + l) * 4]) = p;
        }
        __syncthreads();
        if (tid < 128) {   /* h_next write-out: 16B device-coherent stores */
            int s = tid >> 3, c16 = tid & 7;
            bf16x8 v = *reinterpret_cast<const bf16x8*>(
                &lds[HOUT_OFF + s * 128 + ((c16 ^ (s & 7)) << 4)]);
            const __hip_bfloat16* dst = &hn[(size_t)(sbase + s) * H + rg * 64 + c16 * 8];
            asm volatile("global_store_dwordx4 %0, %1, off sc0 sc1"
                         :: "v"(dst), "v"(v) : "memory");
        }
        if (tid < 16) {   /* this block's logit partial: plain store, no RMW */
            const float* lg = reinterpret_cast<const float*>(&lds[LOGIT_OFF]);
            float ps = lg[tid] + lg[16 + tid] + lg[32 + tid] + lg[48 + tid];
            __hip_atomic_store(&lp[(size_t)(t * 16 + rg) * B + sbase + tid],
                               ps, __ATOMIC_RELAXED, AGENT);
        }

        /* ---- hybrid barrier, with next-step gathers hidden under the wait ---- */
        {
            const unsigned fval = (unsigned)(t + 2);
            asm volatile("s_waitcnt vmcnt(0)" ::: "memory");  /* h + lp stores at MALL */
            __syncthreads();
            if (tid == 0) __hip_atomic_store(&sgf[rg], fval, __ATOMIC_RELAXED, AGENT);

            /* next-step gather chain issues now; results used next epilogue */
            {
                int tn = (t + 1 < T_STEPS) ? t + 1 : t;
                int xc = x_idx[tn * B + sbase + lr];
                int yc = y_idx[tn * B + sbase + lr];
                #pragma unroll
                for (int r = 0; r < 4; ++r) {
                    int gi = rg * 64 + w * 16 + g * 4 + r;
                    wx_r[r] = Wx[(size_t)gi * NIN + xc];
                    wy_r[r] = Wy[(size_t)yc * H + gi];
                }
            }

            if (rg == 0) {
                if (tid < 64) {
                    unsigned v;
                    do {
                        v = (tid < 16) ? __hip_atomic_load(&sgf[tid], __ATOMIC_RELAXED, AGENT) : fval;
                    } while (!__all(v >= fval));
                    if (tid == 0) __hip_atomic_store(&sgf[32], fval, __ATOMIC_RELAXED, AGENT);
                }
            } else if (tid == 0) {
                while (__hip_atomic_load(&sgf[32], __ATOMIC_RELAXED, AGENT) < fval) {}
            }
            __syncthreads();
        }
    }

    /* ---- final: block (rg,sg) handles t = rg, rg+16, ... for its 16 students ---- */
    {
        int ti = tid >> 4, s = tid & 15;
        int t = rg + ti * 16;
        if (t < T_STEPS) {
            int idx = t * B + sbase + s;
            float lgv = 0.f;
            #pragma unroll
            for (int rgi = 0; rgi < 16; ++rgi)
                lgv += __hip_atomic_load(&lp[(size_t)(t * 16 + rgi) * B + sbase + s],
                                         __ATOMIC_RELAXED, AGENT);
            int yc = y_idx[idx];
            lgv += by[yc];
            float pred = 1.f / (1.f + expf(-lgv));
            float tv = truth[idx];
            float e = log1pf(expf(-fabsf(lgv)));
            float ls_pos = fminf(lgv, 0.f) - e;
            float ls_neg = fminf(-lgv, 0.f) - e;
            out[idx] = pred;
            out[T_STEPS * B + idx] = -(tv * ls_pos + (1.f - tv) * ls_neg);
        }
    }
}

extern "C" void kernel_launch(void* const* d_in, const int* in_sizes, int n_in,
                              void* d_out, int out_size, void* d_ws, size_t ws_size,
                              hipStream_t stream) {
    const int*   x_idx   = (const int*)d_in[0];
    const int*   y_idx   = (const int*)d_in[1];
    const float* truth   = (const float*)d_in[2];
    const float* Wm      = (const float*)d_in[3];
    const float* bm      = (const float*)d_in[4];
    const float* Wx      = (const float*)d_in[5];
    const float* bx_     = (const float*)d_in[6];
    const float* Wy      = (const float*)d_in[7];
    const float* by      = (const float*)d_in[8];
    /* d_in[9] = W_start: dead (multiplied by zeros) */
    const float* b_start = (const float*)d_in[10];
    float* out = (float*)d_out;

    __hip_bfloat16* h0buf = (__hip_bfloat16*)((char*)d_ws + H0_OFF);
    __hip_bfloat16* h1buf = (__hip_bfloat16*)((char*)d_ws + H1_OFF);
    float*          lp    = (float*)((char*)d_ws + LP_OFF);
    unsigned*       flags = (unsigned*)((char*)d_ws + FLAG_OFF);

    ws_init<<<4, 256, 0, stream>>>(flags);

    /* plain launch: 256 blocks on 256 CUs are unconditionally co-resident. */
    rnn_persistent<<<dim3(256), dim3(256), SMEM_BYTES, stream>>>(
        x_idx, y_idx, truth, Wm, bm, Wx, bx_, Wy, by, b_start,
        h0buf, h1buf, lp, flags, out);
}